// Round 8
// baseline (289.128 us; speedup 1.0000x reference)
//
#include <hip/hip_runtime.h>
#include <stdint.h>

// Problem constants (B=64, S=512 -> 32768 tokens)
#define N_TOK 32768
#define DIN   512
#define DFF   1024
#define MPAD  33792   // 32768 + 8*128 worst-case bucket padding

// fp8 rotation convention: within each 128B K-window, row data is rotated by
// (row mod 16)*8 bytes: phys = (k & ~127) + (((k&127) + (row&15)*8) & 127).
// Same permutation on A-rows and B-rows => dot product unchanged. Staging is
// then a linear aligned copy; fragment reads cover all 32 banks (conflict-free).
__device__ __forceinline__ int rotk(int k, int row) {
    return (k & ~127) + (((k & 127) + ((row & 15) << 3)) & 127);
}

typedef __attribute__((ext_vector_type(8))) short bf16x8;
typedef __attribute__((ext_vector_type(4))) float f32x4;
typedef __attribute__((ext_vector_type(8))) int   i32x8;

union frag8 { long l[4]; i32x8 v; };

__device__ __forceinline__ unsigned short f2bf(float f) {
    union { float f; unsigned int u; } v; v.f = f;
    unsigned int u = v.u;
    return (unsigned short)((u + 0x7FFFu + ((u >> 16) & 1u)) >> 16);
}
__device__ __forceinline__ float bf2f(unsigned int bits) {
    union { unsigned int u; float f; } v; v.u = bits << 16; return v.f;
}
// pack 4 floats -> 4 OCP e4m3 bytes (hw cvt, saturating)
__device__ __forceinline__ unsigned int pk4_fp8(float a, float b, float c, float d) {
    int v = __builtin_amdgcn_cvt_pk_fp8_f32(a, b, 0, false);
    v = __builtin_amdgcn_cvt_pk_fp8_f32(c, d, v, true);
    return (unsigned int)v;
}
__device__ __forceinline__ unsigned char f2fp8(float a) {
    return (unsigned char)(__builtin_amdgcn_cvt_pk_fp8_f32(a, a, 0, false) & 0xFF);
}

// async 16B global -> LDS (wave-uniform LDS base + lane*16 pattern)
__device__ __forceinline__ void async16(const void* g, void* l) {
    __builtin_amdgcn_global_load_lds(
        (const __attribute__((address_space(1))) void*)g,
        (__attribute__((address_space(3))) void*)l, 16, 0, 0);
}

// ---------------- merged prep: tokens + weights + perm-pad in ONE launch -------
__global__ void prep_kernel(const float* __restrict__ x,
                            unsigned short* __restrict__ Xb,
                            unsigned char* __restrict__ Xb8,
                            const int* __restrict__ types,
                            int* __restrict__ blockhist,
                            const float* __restrict__ Wp,
                            const float* __restrict__ Wt,
                            const float* __restrict__ Wc,
                            unsigned char* __restrict__ Wp8,
                            unsigned char* __restrict__ Wt8,
                            unsigned short* __restrict__ WcT,
                            int* __restrict__ perm) {
    __shared__ float tile[32][33];
    __shared__ int lc[8];
    const int b = blockIdx.x, tid = threadIdx.x;
    if (b < 16384) {
        const int i = b * 1024 + tid * 4;
        float4 v = *(const float4*)(x + i);
        ushort4 o;
        o.x = f2bf(v.x); o.y = f2bf(v.y); o.z = f2bf(v.z); o.w = f2bf(v.w);
        *(ushort4*)(Xb + i) = o;
        const int row = i >> 9;             // DIN=512
        const int k   = i & 511;
        *(unsigned int*)(Xb8 + (size_t)row * DIN + rotk(k, row)) = pk4_fp8(v.x, v.y, v.z, v.w);
        if (b < 64) {
            if (tid < 8) lc[tid] = 0;
            __syncthreads();
            atomicAdd(&lc[types[b * 512 + tid]], 1);
            atomicAdd(&lc[types[b * 512 + 256 + tid]], 1);
            __syncthreads();
            if (tid < 8) blockhist[b * 8 + tid] = lc[tid];
        }
    } else if (b < 26624) {
        const int r = b - 16384;
        const int z = r >> 10;
        const int bx = r & 31, by = (r >> 5) & 31;
        const int tx = tid & 31, ty = tid >> 5;
        const float* s; int K, N;
        if (z == 0)      { s = Wp;                          K = 512;  N = 1024; }
        else if (z <= 8) { s = Wt + (size_t)(z-1)*DIN*DFF;  K = 1024; N = 512; }
        else             { s = Wc;                          K = 512;  N = 512; }
        const int n0 = bx * 32, k0 = by * 32;
        if (n0 >= N || k0 >= K) return;
        for (int i = ty; i < 32; i += 8)
            tile[i][tx] = s[(size_t)(k0 + i) * N + n0 + tx];
        __syncthreads();
        if (z <= 8) {
            // 4B-packed fp8 store: thread owns (1 n, 4 consecutive k)
            unsigned char* d = (z == 0) ? Wp8 : (Wt8 + (size_t)(z-1)*DIN*DFF);
            const int nl = tid >> 3;            // 0..31
            const int k4 = (tid & 7) << 2;      // 0,4,..,28
            const int n  = n0 + nl;
            const int kk = k0 + k4;
            unsigned int pk = pk4_fp8(tile[k4 + 0][nl] * 64.f, tile[k4 + 1][nl] * 64.f,
                                      tile[k4 + 2][nl] * 64.f, tile[k4 + 3][nl] * 64.f);
            *(unsigned int*)(d + (size_t)n * K + rotk(kk, n)) = pk;
        } else {
            for (int i = ty; i < 32; i += 8)
                WcT[(size_t)(n0 + i) * K + k0 + tx] = f2bf(tile[tx][i]);
        }
    } else {
        perm[(b - 26624) * 256 + tid] = -1;
    }
}

// ---- atomic-free scatter: 64 blocks x 512 threads, deterministic placement ----
__global__ void scatter_kernel(const int* __restrict__ types,
                               const int* __restrict__ blockhist,
                               int* __restrict__ perm,
                               int* __restrict__ invperm,
                               float* __restrict__ outz,
                               int* __restrict__ po_out) {
    __shared__ int tots[8], base[8], fill[8];
    const int blk = blockIdx.x;            // 64
    const int tid = threadIdx.x;           // 512
    const int i = blk * 512 + tid;
    outz[i] = 0.f;
    int pre = 0;
    if (tid < 8) {
        int total = 0;
        for (int j = 0; j < 64; j++) {
            int v = blockhist[j * 8 + tid];
            if (j < blk) pre += v;
            total += v;
        }
        tots[tid] = total;
    }
    __syncthreads();
    if (tid < 8) {
        int off = 0, pob = 0;
        #pragma unroll
        for (int t2 = 0; t2 < 8; t2++) {
            if (t2 == tid) pob = off;
            off += ((tots[t2] + 127) >> 7) << 7;
        }
        base[tid] = pob + pre;
        fill[tid] = 0;
        if (blk == 0) {
            po_out[tid] = pob;
            if (tid == 0) po_out[8] = off;
        }
    }
    __syncthreads();
    const int t = types[i];
    const int r = atomicAdd(&fill[t], 1);  // LDS atomic: intra-block rank
    const int p = base[t] + r;
    perm[p] = i;
    invperm[i] = p;
}

// ---------- fp8 GEMM (R8 = R6 revert + 2 bounded deltas) -----------------------
// R7's 128x256 shape thrashed L2 (FETCH +30%, WRITE x1.66) -> reverted to the
// R6-proven 128x128 / 4-wave / MX-scaled / 2-barrier kernel. Deltas vs R6:
//  (1) launch_bounds (256,3) -> (256,4): R6 measured VGPR=84 < 128, so codegen
//      is unchanged; this only lifts the occupancy cap R6 imposed (its one
//      regression: GEMM2 51.2 vs R2's 48.8 at occupancy 19.5 vs 22).
//  (2) GEMM1 gets the same 1D XCD band swizzle as GEMM2 (2048 % 8 == 0,
//      bijective) -- R2-proven to cut cross-XCD A-refetch, time-neutral worst
//      case.
// MX inner (m145/m148 lever): mfma_scale_f32_16x16x128_f8f6f4, unit scales
// (E8M0 127 = 2^0) = same fp8 products at ~2.15x FLOP/cy, one MFMA per
// fragment pair per K-tile. Per-element K-order unchanged -> bit-identical.
// MODE 0 (GEMM1): A=Xb8 token-order; C = fp8(relu*0.125) scattered via
//                 invperm, k-rotated by bucket position p.
// MODE 1 (GEMM2): A=Xff8 bucket-order; B per bucket via po[]; epilogue:
//                 Xb[tok] = bf16(Xb[tok] + relu(acc)/512).
template <int MODE>
__global__ __launch_bounds__(256, 4)
void gemm_fp8_kernel(const unsigned char* __restrict__ A,
                     const unsigned char* __restrict__ B,
                     void* __restrict__ Cout,
                     const unsigned short* __restrict__ xres,
                     const int* __restrict__ pmap,   // MODE0: invperm, MODE1: perm
                     const int* __restrict__ po,     // MODE1 only: padded offsets[9]
                     int K, int ldA) {
    __shared__ unsigned char As[128 * 128];
    __shared__ unsigned char Bs[128 * 128];
    __shared__ int ptile[128];

    const int tid  = threadIdx.x;
    const int wave = tid >> 6;
    const int lane = tid & 63;
    const int quad = lane >> 4;
    const int tl   = lane & 15;
    int m0, n0;
    if constexpr (MODE == 1) {
        // 1056 blocks; XCD-band swizzle (1056 % 8 == 0, bijective)
        const int sid = (blockIdx.x & 7) * 132 + (blockIdx.x >> 3);
        m0 = (sid >> 2) * 128;
        n0 = (sid & 3) * 128;
    } else {
        // 2048 blocks; XCD-band swizzle: XCD k owns 32 m-tiles x all 8 n-tiles
        const int sid = (blockIdx.x & 7) * 256 + (blockIdx.x >> 3);
        m0 = (sid >> 3) * 128;
        n0 = (sid & 7) * 128;
    }
    const int wm = (wave & 1) * 64;
    const int wn = (wave >> 1) * 64;

    const unsigned char* Bp = B;
    if constexpr (MODE == 1) {
        if (m0 >= po[8]) return;                  // fully-padded tail block
        int bsel = 0;
        #pragma unroll
        for (int i = 1; i < 8; i++) bsel += (m0 >= po[i]) ? 1 : 0;
        Bp = B + (size_t)bsel * (DIN * DFF);
    }
    if (tid < 128) ptile[tid] = pmap[m0 + tid];

    f32x4 acc[4][4];
    #pragma unroll
    for (int i = 0; i < 4; i++)
        #pragma unroll
        for (int j = 0; j < 4; j++)
            acc[i][j] = (f32x4){0.f, 0.f, 0.f, 0.f};

    for (int k0 = 0; k0 < K; k0 += 128) {
        __syncthreads();
        // A tile [128][128]: 1024 x 16B chunks, 4/thread, LINEAR copy
        #pragma unroll
        for (int i = 0; i < 4; i++) {
            const int c   = (i * 4 + wave) * 64 + lane;
            const int row = c >> 3;
            const int j   = c & 7;
            async16(A + (size_t)(m0 + row) * ldA + k0 + j * 16, (char*)As + (size_t)c * 16);
        }
        // B tile [128][128], linear
        #pragma unroll
        for (int i = 0; i < 4; i++) {
            const int c   = (i * 4 + wave) * 64 + lane;
            const int row = c >> 3;
            const int j   = c & 7;
            async16(Bp + (size_t)(n0 + row) * K + k0 + j * 16, (char*)Bs + (size_t)c * 16);
        }
        __syncthreads();

        // MX inner: lane covers k in [quad*32, quad*32+32) of this K-tile,
        // read as 4x8B rotated pieces (rotation multiple of 8 -> never wraps).
        frag8 bfr[4];
        #pragma unroll
        for (int nt = 0; nt < 4; nt++) {
            const unsigned char* bp = Bs + (wn + nt * 16 + tl) * 128;
            #pragma unroll
            for (int j = 0; j < 4; j++)
                bfr[nt].l[j] = *(const long*)(bp + ((quad * 32 + j * 8 + tl * 8) & 127));
        }
        #pragma unroll
        for (int mt = 0; mt < 4; mt++) {
            frag8 af;
            const unsigned char* ap = As + (wm + mt * 16 + tl) * 128;
            #pragma unroll
            for (int j = 0; j < 4; j++)
                af.l[j] = *(const long*)(ap + ((quad * 32 + j * 8 + tl * 8) & 127));
            #pragma unroll
            for (int nt = 0; nt < 4; nt++)
                acc[mt][nt] = __builtin_amdgcn_mfma_scale_f32_16x16x128_f8f6f4(
                    bfr[nt].v, af.v, acc[mt][nt],
                    0, 0,          // cbsz=fp8(e4m3), blgp=fp8(e4m3)
                    0, 127,        // scale_a: byte0 = 127 (2^0)
                    0, 127);       // scale_b: byte0 = 127 (2^0)  swapped: D[n][tok]
        }
    }

    // epilogue: lane holds 4 consecutive n (regs) for token tl
    if constexpr (MODE == 0) {
        unsigned char* C8 = (unsigned char*)Cout;
        #pragma unroll
        for (int mt = 0; mt < 4; mt++) {
            const int p = ptile[wm + mt * 16 + tl];            // bucket position
            const size_t rowbase = (size_t)p * DFF;
            const int prot = (p & 15) << 3;
            #pragma unroll
            for (int nt = 0; nt < 4; nt++) {
                const int off = wn + nt * 16 + quad * 4;       // in-window offset
                unsigned int pk = pk4_fp8(fmaxf(acc[mt][nt][0], 0.f) * 0.125f,
                                          fmaxf(acc[mt][nt][1], 0.f) * 0.125f,
                                          fmaxf(acc[mt][nt][2], 0.f) * 0.125f,
                                          fmaxf(acc[mt][nt][3], 0.f) * 0.125f);
                const int phys = (off & ~127) + (((off & 127) + prot) & 127);
                *(unsigned int*)(C8 + rowbase + n0 + phys) = pk;
            }
        }
    } else {
        unsigned short* Cb = (unsigned short*)Cout;
        int toks[4];
        #pragma unroll
        for (int mt = 0; mt < 4; mt++) toks[mt] = ptile[wm + mt * 16 + tl];
        // batch ALL residual loads first (breaks serial dependent chains)
        ushort4 rv[4][4];
        #pragma unroll
        for (int mt = 0; mt < 4; mt++) {
            if (toks[mt] < 0) continue;
            const size_t rowbase = (size_t)toks[mt] * DIN;
            #pragma unroll
            for (int nt = 0; nt < 4; nt++)
                rv[mt][nt] = *(const ushort4*)(xres + rowbase + n0 + wn + nt * 16 + quad * 4);
        }
        #pragma unroll
        for (int mt = 0; mt < 4; mt++) {
            if (toks[mt] < 0) continue;
            const size_t rowbase = (size_t)toks[mt] * DIN;
            #pragma unroll
            for (int nt = 0; nt < 4; nt++) {
                const int ncol = n0 + wn + nt * 16 + quad * 4;
                ushort4 o;
                o.x = f2bf(bf2f(rv[mt][nt].x) + fmaxf(acc[mt][nt][0], 0.f) * 0.001953125f);
                o.y = f2bf(bf2f(rv[mt][nt].y) + fmaxf(acc[mt][nt][1], 0.f) * 0.001953125f);
                o.z = f2bf(bf2f(rv[mt][nt].z) + fmaxf(acc[mt][nt][2], 0.f) * 0.001953125f);
                o.w = f2bf(bf2f(rv[mt][nt].w) + fmaxf(acc[mt][nt][3], 0.f) * 0.001953125f);
                *(ushort4*)(Cb + rowbase + ncol) = o;
            }
        }
    }
}

// ------- bf16 GEMM3 + head (kept full precision): 128x256 tile, 512 thr --------
// out[tok] += relu(Xb @ W_c1) . w2   (atomicAdd partials per n-block)
// 1D grid + XCD-band swizzle (512 % 8 == 0).
__global__ __launch_bounds__(512, 4)
void gemm3_kernel(const unsigned short* __restrict__ A,
                  const unsigned short* __restrict__ B,
                  const float* __restrict__ w2,
                  float* __restrict__ outp,
                  int K, int ldA) {
    __shared__ unsigned short As[128 * 64];
    __shared__ unsigned short Bs[256 * 64];

    const int tid  = threadIdx.x;
    const int wave = tid >> 6;
    const int lane = tid & 63;
    const int quad = lane >> 4;
    const int tl   = lane & 15;
    const int sid = (blockIdx.x & 7) * 64 + (blockIdx.x >> 3);
    const int m0 = (sid >> 1) * 128;
    const int n0 = (sid & 1) * 256;
    const int wm = (wave & 1) * 64;
    const int wn = (wave >> 1) * 64;

    f32x4 acc[4][4];
    #pragma unroll
    for (int i = 0; i < 4; i++)
        #pragma unroll
        for (int j = 0; j < 4; j++)
            acc[i][j] = (f32x4){0.f, 0.f, 0.f, 0.f};

    for (int k0 = 0; k0 < K; k0 += 64) {
        __syncthreads();
        #pragma unroll
        for (int i = 0; i < 2; i++) {
            const int c   = (i * 8 + wave) * 64 + lane;
            const int row = c >> 3;
            const int gj  = (c & 7) ^ (row & 7);
            async16(A + (size_t)(m0 + row) * ldA + k0 + gj * 8, (char*)As + (size_t)c * 16);
        }
        #pragma unroll
        for (int i = 0; i < 4; i++) {
            const int c   = (i * 8 + wave) * 64 + lane;
            const int row = c >> 3;
            const int gj  = (c & 7) ^ (row & 7);
            async16(B + (size_t)(n0 + row) * K + k0 + gj * 8, (char*)Bs + (size_t)c * 16);
        }
        __syncthreads();

        #pragma unroll
        for (int ks = 0; ks < 2; ks++) {
            bf16x8 af[4], bfr[4];
            const int jc = ks * 4 + quad;
            #pragma unroll
            for (int t = 0; t < 4; t++) {
                const int r = wm + t * 16 + tl;
                af[t] = *(const bf16x8*)(As + (r * 8 + (jc ^ (r & 7))) * 8);
            }
            #pragma unroll
            for (int t = 0; t < 4; t++) {
                const int r = wn + t * 16 + tl;
                bfr[t] = *(const bf16x8*)(Bs + (r * 8 + (jc ^ (r & 7))) * 8);
            }
            #pragma unroll
            for (int mt = 0; mt < 4; mt++)
                #pragma unroll
                for (int nt = 0; nt < 4; nt++)
                    acc[mt][nt] = __builtin_amdgcn_mfma_f32_16x16x32_bf16(
                        bfr[nt], af[mt], acc[mt][nt], 0, 0, 0);
        }
    }

    float4 w2v[4];
    #pragma unroll
    for (int nt = 0; nt < 4; nt++)
        w2v[nt] = *(const float4*)(w2 + n0 + wn + nt * 16 + quad * 4);
    #pragma unroll
    for (int mt = 0; mt < 4; mt++) {
        float s = 0.f;
        #pragma unroll
        for (int nt = 0; nt < 4; nt++) {
            s += fmaxf(acc[mt][nt][0], 0.f) * w2v[nt].x;
            s += fmaxf(acc[mt][nt][1], 0.f) * w2v[nt].y;
            s += fmaxf(acc[mt][nt][2], 0.f) * w2v[nt].z;
            s += fmaxf(acc[mt][nt][3], 0.f) * w2v[nt].w;
        }
        s += __shfl_down(s, 32);
        s += __shfl_down(s, 16);
        if (lane < 16) atomicAdd(&outp[m0 + wm + mt * 16 + lane], s);
    }
}

extern "C" void kernel_launch(void* const* d_in, const int* in_sizes, int n_in,
                              void* d_out, int out_size, void* d_ws, size_t ws_size,
                              hipStream_t stream) {
    const float* x      = (const float*)d_in[0];
    const int*   types  = (const int*)d_in[1];
    const float* W_pre  = (const float*)d_in[2];
    const float* W_types= (const float*)d_in[3];
    const float* W_c1   = (const float*)d_in[4];
    const float* W_c2   = (const float*)d_in[5];
    float* out = (float*)d_out;

    // workspace layout (~91 MB):
    char* ws = (char*)d_ws;
    unsigned short* Xb  = (unsigned short*)(ws);                    // bf16 [32768][512], becomes X_res
    unsigned char*  Xff8= (unsigned char*)(ws + 33554432ull);       // fp8 [MPAD][1024] = 8*x_, bucket order, k-rotated
    unsigned char*  Xb8 = (unsigned char*)(ws + 68157440ull);       // fp8 [32768][512] = x, k-rotated
    unsigned char*  Wp8 = (unsigned char*)(ws + 84934656ull);       // fp8 [1024][512] (x64, rotated)
    unsigned char*  Wt8 = (unsigned char*)(ws + 85458944ull);       // fp8 [8][512][1024] (x64, rotated)
    unsigned short* WcT = (unsigned short*)(ws + 89653248ull);      // bf16 [512][512]
    int* perm           = (int*)(ws + 90177536ull);                  // MPAD ints
    int* invperm        = (int*)(ws + 90312704ull);                  // N_TOK ints
    int* po             = (int*)(ws + 90443776ull);                  // 9 ints (padded offsets)
    int* blockhist      = po + 16;                                   // 64*8 ints

    // 1) merged prep: tokens [0,16384), weights [16384,26624), perm-pad [26624,26756)
    prep_kernel<<<26756, 256, 0, stream>>>(x, Xb, Xb8, types, blockhist,
                                           W_pre, W_types, W_c1, Wp8, Wt8, WcT, perm);
    // 2) deterministic scatter + po publish + out zero
    scatter_kernel<<<64, 512, 0, stream>>>(types, blockhist, perm, invperm, out, po);
    // 3) GEMM1 (fp8 MX, R6 shape + XCD band): Xff8[invperm[tok]] = fp8(8 * relu(x @ W_pre))
    gemm_fp8_kernel<0><<<2048, 256, 0, stream>>>(
        Xb8, Wp8, Xff8, nullptr, invperm, nullptr, 512, 512);
    // 4) GEMM2 (fp8 MX, routed, R6 shape, XCD band): Xb = bf16(Xb + relu(Xff8 @ Wt8[b]) / 512)
    gemm_fp8_kernel<1><<<1056, 256, 0, stream>>>(
        Xff8, Wt8, Xb, Xb, perm, po, 1024, 1024);
    // 5) GEMM3 + head (bf16, XCD-banded 1D grid): out = relu(Xb @ W_c1) @ W_c2
    gemm3_kernel<<<512, 512, 0, stream>>>(
        Xb, WcT, W_c2, out, 512, 512);
}

// Round 9
// 217.935 us; speedup vs baseline: 1.3267x; 1.3267x over previous
//
#include <hip/hip_runtime.h>
#include <stdint.h>

// Problem constants (B=64, S=512 -> 32768 tokens)
#define N_TOK 32768
#define DIN   512
#define DFF   1024
#define MPAD  33792   // 32768 + 8*128 worst-case bucket padding

// fp8 rotation convention: within each 128B K-window, row data is rotated by
// (row mod 16)*8 bytes: phys = (k & ~127) + (((k&127) + (row&15)*8) & 127).
// Same permutation on A-rows and B-rows => dot product unchanged. Staging is
// then a linear aligned copy; fragment reads cover all 32 banks (conflict-free).
__device__ __forceinline__ int rotk(int k, int row) {
    return (k & ~127) + (((k & 127) + ((row & 15) << 3)) & 127);
}

typedef __attribute__((ext_vector_type(8))) short bf16x8;
typedef __attribute__((ext_vector_type(4))) float f32x4;
typedef __attribute__((ext_vector_type(8))) int   i32x8;

union frag8 { long l[4]; i32x8 v; };

__device__ __forceinline__ unsigned short f2bf(float f) {
    union { float f; unsigned int u; } v; v.f = f;
    unsigned int u = v.u;
    return (unsigned short)((u + 0x7FFFu + ((u >> 16) & 1u)) >> 16);
}
__device__ __forceinline__ float bf2f(unsigned int bits) {
    union { unsigned int u; float f; } v; v.u = bits << 16; return v.f;
}
// pack 4 floats -> 4 OCP e4m3 bytes (hw cvt, saturating)
__device__ __forceinline__ unsigned int pk4_fp8(float a, float b, float c, float d) {
    int v = __builtin_amdgcn_cvt_pk_fp8_f32(a, b, 0, false);
    v = __builtin_amdgcn_cvt_pk_fp8_f32(c, d, v, true);
    return (unsigned int)v;
}
__device__ __forceinline__ unsigned char f2fp8(float a) {
    return (unsigned char)(__builtin_amdgcn_cvt_pk_fp8_f32(a, a, 0, false) & 0xFF);
}

// async 16B global -> LDS (wave-uniform LDS base + lane*16 pattern)
__device__ __forceinline__ void async16(const void* g, void* l) {
    __builtin_amdgcn_global_load_lds(
        (const __attribute__((address_space(1))) void*)g,
        (__attribute__((address_space(3))) void*)l, 16, 0, 0);
}

// ---------------- merged prep: tokens + weights + perm-pad in ONE launch -------
__global__ void prep_kernel(const float* __restrict__ x,
                            unsigned short* __restrict__ Xb,
                            unsigned char* __restrict__ Xb8,
                            const int* __restrict__ types,
                            int* __restrict__ blockhist,
                            const float* __restrict__ Wp,
                            const float* __restrict__ Wt,
                            const float* __restrict__ Wc,
                            unsigned char* __restrict__ Wp8,
                            unsigned char* __restrict__ Wt8,
                            unsigned short* __restrict__ WcT,
                            int* __restrict__ perm) {
    __shared__ float tile[32][33];
    __shared__ int lc[8];
    const int b = blockIdx.x, tid = threadIdx.x;
    if (b < 16384) {
        const int i = b * 1024 + tid * 4;
        float4 v = *(const float4*)(x + i);
        ushort4 o;
        o.x = f2bf(v.x); o.y = f2bf(v.y); o.z = f2bf(v.z); o.w = f2bf(v.w);
        *(ushort4*)(Xb + i) = o;
        const int row = i >> 9;             // DIN=512
        const int k   = i & 511;
        *(unsigned int*)(Xb8 + (size_t)row * DIN + rotk(k, row)) = pk4_fp8(v.x, v.y, v.z, v.w);
        if (b < 64) {
            if (tid < 8) lc[tid] = 0;
            __syncthreads();
            atomicAdd(&lc[types[b * 512 + tid]], 1);
            atomicAdd(&lc[types[b * 512 + 256 + tid]], 1);
            __syncthreads();
            if (tid < 8) blockhist[b * 8 + tid] = lc[tid];
        }
    } else if (b < 26624) {
        const int r = b - 16384;
        const int z = r >> 10;
        const int bx = r & 31, by = (r >> 5) & 31;
        const int tx = tid & 31, ty = tid >> 5;
        const float* s; int K, N;
        if (z == 0)      { s = Wp;                          K = 512;  N = 1024; }
        else if (z <= 8) { s = Wt + (size_t)(z-1)*DIN*DFF;  K = 1024; N = 512; }
        else             { s = Wc;                          K = 512;  N = 512; }
        const int n0 = bx * 32, k0 = by * 32;
        if (n0 >= N || k0 >= K) return;
        for (int i = ty; i < 32; i += 8)
            tile[i][tx] = s[(size_t)(k0 + i) * N + n0 + tx];
        __syncthreads();
        if (z <= 8) {
            // 4B-packed fp8 store: thread owns (1 n, 4 consecutive k)
            unsigned char* d = (z == 0) ? Wp8 : (Wt8 + (size_t)(z-1)*DIN*DFF);
            const int nl = tid >> 3;            // 0..31
            const int k4 = (tid & 7) << 2;      // 0,4,..,28
            const int n  = n0 + nl;
            const int kk = k0 + k4;
            unsigned int pk = pk4_fp8(tile[k4 + 0][nl] * 64.f, tile[k4 + 1][nl] * 64.f,
                                      tile[k4 + 2][nl] * 64.f, tile[k4 + 3][nl] * 64.f);
            *(unsigned int*)(d + (size_t)n * K + rotk(kk, n)) = pk;
        } else {
            for (int i = ty; i < 32; i += 8)
                WcT[(size_t)(n0 + i) * K + k0 + tx] = f2bf(tile[tx][i]);
        }
    } else {
        perm[(b - 26624) * 256 + tid] = -1;
    }
}

// ---- atomic-free scatter: 64 blocks x 512 threads, deterministic placement ----
__global__ void scatter_kernel(const int* __restrict__ types,
                               const int* __restrict__ blockhist,
                               int* __restrict__ perm,
                               int* __restrict__ invperm,
                               float* __restrict__ outz,
                               int* __restrict__ po_out) {
    __shared__ int tots[8], base[8], fill[8];
    const int blk = blockIdx.x;            // 64
    const int tid = threadIdx.x;           // 512
    const int i = blk * 512 + tid;
    outz[i] = 0.f;
    int pre = 0;
    if (tid < 8) {
        int total = 0;
        for (int j = 0; j < 64; j++) {
            int v = blockhist[j * 8 + tid];
            if (j < blk) pre += v;
            total += v;
        }
        tots[tid] = total;
    }
    __syncthreads();
    if (tid < 8) {
        int off = 0, pob = 0;
        #pragma unroll
        for (int t2 = 0; t2 < 8; t2++) {
            if (t2 == tid) pob = off;
            off += ((tots[t2] + 127) >> 7) << 7;
        }
        base[tid] = pob + pre;
        fill[tid] = 0;
        if (blk == 0) {
            po_out[tid] = pob;
            if (tid == 0) po_out[8] = off;
        }
    }
    __syncthreads();
    const int t = types[i];
    const int r = atomicAdd(&fill[t], 1);  // LDS atomic: intra-block rank
    const int p = base[t] + r;
    perm[p] = i;
    invperm[i] = p;
}

// ---------- fp8 GEMM (R9 = exact R6 body; single delta = GEMM1 grid swizzle) ---
// R8 lesson (HW): the MX kernel's combined VGPR+AGPR floor is ~170 regs ->
// launch_bounds(256,3) is the ONLY valid setting. (256,4)/(512,4) split the
// 128-reg budget 64V+64A and SPILLED (VGPR_Count 64, WRITE 33->58.7 MB =
// scratch traffic, dur 51->87 us). Do not touch launch_bounds again.
// Body identical to R6 (224.9 us best). MX inner (m145/m148): one
// mfma_scale_f32_16x16x128_f8f6f4 with unit scales (E8M0 127 = 2^0) per
// fragment pair per K-tile; per-element K-order unchanged -> bit-identical.
// MODE 0 (GEMM1): 1D 2048-block grid + XCD band swizzle (THE one R9 delta;
//                 compile-time-invariant, R2-proven mechanism: A-panel 2MB/XCD
//                 stays L2-resident across its 8 n-reuses). A=Xb8 token-order;
//                 C = fp8(relu*0.125) scattered via invperm, k-rotated by p.
// MODE 1 (GEMM2): exact R6: 1D 1056 XCD-banded; A=Xff8 bucket-order; B per
//                 bucket via po[]; epilogue: Xb[tok] += relu(acc)/512.
template <int MODE>
__global__ __launch_bounds__(256, 3)
void gemm_fp8_kernel(const unsigned char* __restrict__ A,
                     const unsigned char* __restrict__ B,
                     void* __restrict__ Cout,
                     const unsigned short* __restrict__ xres,
                     const int* __restrict__ pmap,   // MODE0: invperm, MODE1: perm
                     const int* __restrict__ po,     // MODE1 only: padded offsets[9]
                     int K, int ldA) {
    __shared__ unsigned char As[128 * 128];
    __shared__ unsigned char Bs[128 * 128];
    __shared__ int ptile[128];

    const int tid  = threadIdx.x;
    const int wave = tid >> 6;
    const int lane = tid & 63;
    const int quad = lane >> 4;
    const int tl   = lane & 15;
    int m0, n0;
    if constexpr (MODE == 1) {
        // 1056 blocks; XCD-band swizzle (1056 % 8 == 0, bijective)
        const int sid = (blockIdx.x & 7) * 132 + (blockIdx.x >> 3);
        m0 = (sid >> 2) * 128;
        n0 = (sid & 3) * 128;
    } else {
        // 2048 blocks; XCD-band swizzle: XCD k owns 32 m-tiles x all 8 n-tiles
        const int sid = (blockIdx.x & 7) * 256 + (blockIdx.x >> 3);
        m0 = (sid >> 3) * 128;
        n0 = (sid & 7) * 128;
    }
    const int wm = (wave & 1) * 64;
    const int wn = (wave >> 1) * 64;

    const unsigned char* Bp = B;
    if constexpr (MODE == 1) {
        if (m0 >= po[8]) return;                  // fully-padded tail block
        int bsel = 0;
        #pragma unroll
        for (int i = 1; i < 8; i++) bsel += (m0 >= po[i]) ? 1 : 0;
        Bp = B + (size_t)bsel * (DIN * DFF);
    }
    if (tid < 128) ptile[tid] = pmap[m0 + tid];

    f32x4 acc[4][4];
    #pragma unroll
    for (int i = 0; i < 4; i++)
        #pragma unroll
        for (int j = 0; j < 4; j++)
            acc[i][j] = (f32x4){0.f, 0.f, 0.f, 0.f};

    for (int k0 = 0; k0 < K; k0 += 128) {
        __syncthreads();
        // A tile [128][128]: 1024 x 16B chunks, 4/thread, LINEAR copy
        #pragma unroll
        for (int i = 0; i < 4; i++) {
            const int c   = (i * 4 + wave) * 64 + lane;
            const int row = c >> 3;
            const int j   = c & 7;
            async16(A + (size_t)(m0 + row) * ldA + k0 + j * 16, (char*)As + (size_t)c * 16);
        }
        // B tile [128][128], linear
        #pragma unroll
        for (int i = 0; i < 4; i++) {
            const int c   = (i * 4 + wave) * 64 + lane;
            const int row = c >> 3;
            const int j   = c & 7;
            async16(Bp + (size_t)(n0 + row) * K + k0 + j * 16, (char*)Bs + (size_t)c * 16);
        }
        __syncthreads();

        // MX inner: lane covers k in [quad*32, quad*32+32) of this K-tile,
        // read as 4x8B rotated pieces (rotation multiple of 8 -> never wraps).
        frag8 bfr[4];
        #pragma unroll
        for (int nt = 0; nt < 4; nt++) {
            const unsigned char* bp = Bs + (wn + nt * 16 + tl) * 128;
            #pragma unroll
            for (int j = 0; j < 4; j++)
                bfr[nt].l[j] = *(const long*)(bp + ((quad * 32 + j * 8 + tl * 8) & 127));
        }
        #pragma unroll
        for (int mt = 0; mt < 4; mt++) {
            frag8 af;
            const unsigned char* ap = As + (wm + mt * 16 + tl) * 128;
            #pragma unroll
            for (int j = 0; j < 4; j++)
                af.l[j] = *(const long*)(ap + ((quad * 32 + j * 8 + tl * 8) & 127));
            #pragma unroll
            for (int nt = 0; nt < 4; nt++)
                acc[mt][nt] = __builtin_amdgcn_mfma_scale_f32_16x16x128_f8f6f4(
                    bfr[nt].v, af.v, acc[mt][nt],
                    0, 0,          // cbsz=fp8(e4m3), blgp=fp8(e4m3)
                    0, 127,        // scale_a: byte0 = 127 (2^0)
                    0, 127);       // scale_b: byte0 = 127 (2^0)  swapped: D[n][tok]
        }
    }

    // epilogue: lane holds 4 consecutive n (regs) for token tl
    if constexpr (MODE == 0) {
        unsigned char* C8 = (unsigned char*)Cout;
        #pragma unroll
        for (int mt = 0; mt < 4; mt++) {
            const int p = ptile[wm + mt * 16 + tl];            // bucket position
            const size_t rowbase = (size_t)p * DFF;
            const int prot = (p & 15) << 3;
            #pragma unroll
            for (int nt = 0; nt < 4; nt++) {
                const int off = wn + nt * 16 + quad * 4;       // in-window offset
                unsigned int pk = pk4_fp8(fmaxf(acc[mt][nt][0], 0.f) * 0.125f,
                                          fmaxf(acc[mt][nt][1], 0.f) * 0.125f,
                                          fmaxf(acc[mt][nt][2], 0.f) * 0.125f,
                                          fmaxf(acc[mt][nt][3], 0.f) * 0.125f);
                const int phys = (off & ~127) + (((off & 127) + prot) & 127);
                *(unsigned int*)(C8 + rowbase + n0 + phys) = pk;
            }
        }
    } else {
        unsigned short* Cb = (unsigned short*)Cout;
        int toks[4];
        #pragma unroll
        for (int mt = 0; mt < 4; mt++) toks[mt] = ptile[wm + mt * 16 + tl];
        // batch ALL residual loads first (breaks serial dependent chains)
        ushort4 rv[4][4];
        #pragma unroll
        for (int mt = 0; mt < 4; mt++) {
            if (toks[mt] < 0) continue;
            const size_t rowbase = (size_t)toks[mt] * DIN;
            #pragma unroll
            for (int nt = 0; nt < 4; nt++)
                rv[mt][nt] = *(const ushort4*)(xres + rowbase + n0 + wn + nt * 16 + quad * 4);
        }
        #pragma unroll
        for (int mt = 0; mt < 4; mt++) {
            if (toks[mt] < 0) continue;
            const size_t rowbase = (size_t)toks[mt] * DIN;
            #pragma unroll
            for (int nt = 0; nt < 4; nt++) {
                const int ncol = n0 + wn + nt * 16 + quad * 4;
                ushort4 o;
                o.x = f2bf(bf2f(rv[mt][nt].x) + fmaxf(acc[mt][nt][0], 0.f) * 0.001953125f);
                o.y = f2bf(bf2f(rv[mt][nt].y) + fmaxf(acc[mt][nt][1], 0.f) * 0.001953125f);
                o.z = f2bf(bf2f(rv[mt][nt].z) + fmaxf(acc[mt][nt][2], 0.f) * 0.001953125f);
                o.w = f2bf(bf2f(rv[mt][nt].w) + fmaxf(acc[mt][nt][3], 0.f) * 0.001953125f);
                *(ushort4*)(Cb + rowbase + ncol) = o;
            }
        }
    }
}

// ------- bf16 GEMM3 + head (kept full precision): 128x256 tile, 512 thr --------
// out[tok] += relu(Xb @ W_c1) . w2   (atomicAdd partials per n-block)
// 1D grid + XCD-band swizzle (512 % 8 == 0).
__global__ __launch_bounds__(512, 4)
void gemm3_kernel(const unsigned short* __restrict__ A,
                  const unsigned short* __restrict__ B,
                  const float* __restrict__ w2,
                  float* __restrict__ outp,
                  int K, int ldA) {
    __shared__ unsigned short As[128 * 64];
    __shared__ unsigned short Bs[256 * 64];

    const int tid  = threadIdx.x;
    const int wave = tid >> 6;
    const int lane = tid & 63;
    const int quad = lane >> 4;
    const int tl   = lane & 15;
    const int sid = (blockIdx.x & 7) * 64 + (blockIdx.x >> 3);
    const int m0 = (sid >> 1) * 128;
    const int n0 = (sid & 1) * 256;
    const int wm = (wave & 1) * 64;
    const int wn = (wave >> 1) * 64;

    f32x4 acc[4][4];
    #pragma unroll
    for (int i = 0; i < 4; i++)
        #pragma unroll
        for (int j = 0; j < 4; j++)
            acc[i][j] = (f32x4){0.f, 0.f, 0.f, 0.f};

    for (int k0 = 0; k0 < K; k0 += 64) {
        __syncthreads();
        #pragma unroll
        for (int i = 0; i < 2; i++) {
            const int c   = (i * 8 + wave) * 64 + lane;
            const int row = c >> 3;
            const int gj  = (c & 7) ^ (row & 7);
            async16(A + (size_t)(m0 + row) * ldA + k0 + gj * 8, (char*)As + (size_t)c * 16);
        }
        #pragma unroll
        for (int i = 0; i < 4; i++) {
            const int c   = (i * 8 + wave) * 64 + lane;
            const int row = c >> 3;
            const int gj  = (c & 7) ^ (row & 7);
            async16(B + (size_t)(n0 + row) * K + k0 + gj * 8, (char*)Bs + (size_t)c * 16);
        }
        __syncthreads();

        #pragma unroll
        for (int ks = 0; ks < 2; ks++) {
            bf16x8 af[4], bfr[4];
            const int jc = ks * 4 + quad;
            #pragma unroll
            for (int t = 0; t < 4; t++) {
                const int r = wm + t * 16 + tl;
                af[t] = *(const bf16x8*)(As + (r * 8 + (jc ^ (r & 7))) * 8);
            }
            #pragma unroll
            for (int t = 0; t < 4; t++) {
                const int r = wn + t * 16 + tl;
                bfr[t] = *(const bf16x8*)(Bs + (r * 8 + (jc ^ (r & 7))) * 8);
            }
            #pragma unroll
            for (int mt = 0; mt < 4; mt++)
                #pragma unroll
                for (int nt = 0; nt < 4; nt++)
                    acc[mt][nt] = __builtin_amdgcn_mfma_f32_16x16x32_bf16(
                        bfr[nt], af[mt], acc[mt][nt], 0, 0, 0);
        }
    }

    float4 w2v[4];
    #pragma unroll
    for (int nt = 0; nt < 4; nt++)
        w2v[nt] = *(const float4*)(w2 + n0 + wn + nt * 16 + quad * 4);
    #pragma unroll
    for (int mt = 0; mt < 4; mt++) {
        float s = 0.f;
        #pragma unroll
        for (int nt = 0; nt < 4; nt++) {
            s += fmaxf(acc[mt][nt][0], 0.f) * w2v[nt].x;
            s += fmaxf(acc[mt][nt][1], 0.f) * w2v[nt].y;
            s += fmaxf(acc[mt][nt][2], 0.f) * w2v[nt].z;
            s += fmaxf(acc[mt][nt][3], 0.f) * w2v[nt].w;
        }
        s += __shfl_down(s, 32);
        s += __shfl_down(s, 16);
        if (lane < 16) atomicAdd(&outp[m0 + wm + mt * 16 + lane], s);
    }
}

extern "C" void kernel_launch(void* const* d_in, const int* in_sizes, int n_in,
                              void* d_out, int out_size, void* d_ws, size_t ws_size,
                              hipStream_t stream) {
    const float* x      = (const float*)d_in[0];
    const int*   types  = (const int*)d_in[1];
    const float* W_pre  = (const float*)d_in[2];
    const float* W_types= (const float*)d_in[3];
    const float* W_c1   = (const float*)d_in[4];
    const float* W_c2   = (const float*)d_in[5];
    float* out = (float*)d_out;

    // workspace layout (~91 MB):
    char* ws = (char*)d_ws;
    unsigned short* Xb  = (unsigned short*)(ws);                    // bf16 [32768][512], becomes X_res
    unsigned char*  Xff8= (unsigned char*)(ws + 33554432ull);       // fp8 [MPAD][1024] = 8*x_, bucket order, k-rotated
    unsigned char*  Xb8 = (unsigned char*)(ws + 68157440ull);       // fp8 [32768][512] = x, k-rotated
    unsigned char*  Wp8 = (unsigned char*)(ws + 84934656ull);       // fp8 [1024][512] (x64, rotated)
    unsigned char*  Wt8 = (unsigned char*)(ws + 85458944ull);       // fp8 [8][512][1024] (x64, rotated)
    unsigned short* WcT = (unsigned short*)(ws + 89653248ull);      // bf16 [512][512]
    int* perm           = (int*)(ws + 90177536ull);                  // MPAD ints
    int* invperm        = (int*)(ws + 90312704ull);                  // N_TOK ints
    int* po             = (int*)(ws + 90443776ull);                  // 9 ints (padded offsets)
    int* blockhist      = po + 16;                                   // 64*8 ints

    // 1) merged prep: tokens [0,16384), weights [16384,26624), perm-pad [26624,26756)
    prep_kernel<<<26756, 256, 0, stream>>>(x, Xb, Xb8, types, blockhist,
                                           W_pre, W_types, W_c1, Wp8, Wt8, WcT, perm);
    // 2) deterministic scatter + po publish + out zero
    scatter_kernel<<<64, 512, 0, stream>>>(types, blockhist, perm, invperm, out, po);
    // 3) GEMM1 (fp8 MX, R6 body, XCD-banded grid): Xff8[invperm[tok]] = fp8(8 * relu(x @ W_pre))
    gemm_fp8_kernel<0><<<2048, 256, 0, stream>>>(
        Xb8, Wp8, Xff8, nullptr, invperm, nullptr, 512, 512);
    // 4) GEMM2 (fp8 MX, routed, exact R6): Xb = bf16(Xb + relu(Xff8 @ Wt8[b]) / 512)
    gemm_fp8_kernel<1><<<1056, 256, 0, stream>>>(
        Xff8, Wt8, Xb, Xb, perm, po, 1024, 1024);
    // 5) GEMM3 + head (bf16, XCD-banded 1D grid): out = relu(Xb @ W_c1) @ W_c2
    gemm3_kernel<<<512, 512, 0, stream>>>(
        Xb, WcT, W_c2, out, 512, 512);
}

// Round 11
// 217.035 us; speedup vs baseline: 1.3322x; 1.0041x over previous
//
#include <hip/hip_runtime.h>
#include <stdint.h>

// Problem constants (B=64, S=512 -> 32768 tokens)
#define N_TOK 32768
#define DIN   512
#define DFF   1024
#define MPAD  33792   // 32768 + 8*128 worst-case bucket padding

// fp8 rotation convention: within each 128B K-window, row data is rotated by
// (row mod 16)*8 bytes: phys = (k & ~127) + (((k&127) + (row&15)*8) & 127).
// Same permutation on A-rows and B-rows => dot product unchanged. Staging is
// then a linear aligned copy; fragment reads cover all 32 banks (conflict-free).
__device__ __forceinline__ int rotk(int k, int row) {
    return (k & ~127) + (((k & 127) + ((row & 15) << 3)) & 127);
}

typedef __attribute__((ext_vector_type(8))) short bf16x8;
typedef __attribute__((ext_vector_type(4))) float f32x4;
typedef __attribute__((ext_vector_type(8))) int   i32x8;

union frag8 { long l[4]; i32x8 v; };

__device__ __forceinline__ unsigned short f2bf(float f) {
    union { float f; unsigned int u; } v; v.f = f;
    unsigned int u = v.u;
    return (unsigned short)((u + 0x7FFFu + ((u >> 16) & 1u)) >> 16);
}
__device__ __forceinline__ float bf2f(unsigned int bits) {
    union { unsigned int u; float f; } v; v.u = bits << 16; return v.f;
}
// pack 4 floats -> 4 OCP e4m3 bytes (hw cvt, saturating)
__device__ __forceinline__ unsigned int pk4_fp8(float a, float b, float c, float d) {
    int v = __builtin_amdgcn_cvt_pk_fp8_f32(a, b, 0, false);
    v = __builtin_amdgcn_cvt_pk_fp8_f32(c, d, v, true);
    return (unsigned int)v;
}
__device__ __forceinline__ unsigned char f2fp8(float a) {
    return (unsigned char)(__builtin_amdgcn_cvt_pk_fp8_f32(a, a, 0, false) & 0xFF);
}

// async 16B global -> LDS (wave-uniform LDS base + lane*16 pattern)
__device__ __forceinline__ void async16(const void* g, void* l) {
    __builtin_amdgcn_global_load_lds(
        (const __attribute__((address_space(1))) void*)g,
        (__attribute__((address_space(3))) void*)l, 16, 0, 0);
}

// ---------------- merged prep: tokens + weights + perm-pad in ONE launch -------
__global__ void prep_kernel(const float* __restrict__ x,
                            unsigned short* __restrict__ Xb,
                            unsigned char* __restrict__ Xb8,
                            const int* __restrict__ types,
                            int* __restrict__ blockhist,
                            const float* __restrict__ Wp,
                            const float* __restrict__ Wt,
                            const float* __restrict__ Wc,
                            unsigned char* __restrict__ Wp8,
                            unsigned char* __restrict__ Wt8,
                            unsigned short* __restrict__ WcT,
                            int* __restrict__ perm) {
    __shared__ float tile[32][33];
    __shared__ int lc[8];
    const int b = blockIdx.x, tid = threadIdx.x;
    if (b < 16384) {
        const int i = b * 1024 + tid * 4;
        float4 v = *(const float4*)(x + i);
        ushort4 o;
        o.x = f2bf(v.x); o.y = f2bf(v.y); o.z = f2bf(v.z); o.w = f2bf(v.w);
        *(ushort4*)(Xb + i) = o;
        const int row = i >> 9;             // DIN=512
        const int k   = i & 511;
        *(unsigned int*)(Xb8 + (size_t)row * DIN + rotk(k, row)) = pk4_fp8(v.x, v.y, v.z, v.w);
        if (b < 64) {
            if (tid < 8) lc[tid] = 0;
            __syncthreads();
            atomicAdd(&lc[types[b * 512 + tid]], 1);
            atomicAdd(&lc[types[b * 512 + 256 + tid]], 1);
            __syncthreads();
            if (tid < 8) blockhist[b * 8 + tid] = lc[tid];
        }
    } else if (b < 26624) {
        const int r = b - 16384;
        const int z = r >> 10;
        const int bx = r & 31, by = (r >> 5) & 31;
        const int tx = tid & 31, ty = tid >> 5;
        const float* s; int K, N;
        if (z == 0)      { s = Wp;                          K = 512;  N = 1024; }
        else if (z <= 8) { s = Wt + (size_t)(z-1)*DIN*DFF;  K = 1024; N = 512; }
        else             { s = Wc;                          K = 512;  N = 512; }
        const int n0 = bx * 32, k0 = by * 32;
        if (n0 >= N || k0 >= K) return;
        for (int i = ty; i < 32; i += 8)
            tile[i][tx] = s[(size_t)(k0 + i) * N + n0 + tx];
        __syncthreads();
        if (z <= 8) {
            // 4B-packed fp8 store: thread owns (1 n, 4 consecutive k)
            unsigned char* d = (z == 0) ? Wp8 : (Wt8 + (size_t)(z-1)*DIN*DFF);
            const int nl = tid >> 3;            // 0..31
            const int k4 = (tid & 7) << 2;      // 0,4,..,28
            const int n  = n0 + nl;
            const int kk = k0 + k4;
            unsigned int pk = pk4_fp8(tile[k4 + 0][nl] * 64.f, tile[k4 + 1][nl] * 64.f,
                                      tile[k4 + 2][nl] * 64.f, tile[k4 + 3][nl] * 64.f);
            *(unsigned int*)(d + (size_t)n * K + rotk(kk, n)) = pk;
        } else {
            for (int i = ty; i < 32; i += 8)
                WcT[(size_t)(n0 + i) * K + k0 + tx] = f2bf(tile[tx][i]);
        }
    } else {
        perm[(b - 26624) * 256 + tid] = -1;
    }
}

// ---- atomic-free scatter: 64 blocks x 512 threads, deterministic placement ----
__global__ void scatter_kernel(const int* __restrict__ types,
                               const int* __restrict__ blockhist,
                               int* __restrict__ perm,
                               int* __restrict__ invperm,
                               float* __restrict__ outz,
                               int* __restrict__ po_out) {
    __shared__ int tots[8], base[8], fill[8];
    const int blk = blockIdx.x;            // 64
    const int tid = threadIdx.x;           // 512
    const int i = blk * 512 + tid;
    outz[i] = 0.f;
    int pre = 0;
    if (tid < 8) {
        int total = 0;
        for (int j = 0; j < 64; j++) {
            int v = blockhist[j * 8 + tid];
            if (j < blk) pre += v;
            total += v;
        }
        tots[tid] = total;
    }
    __syncthreads();
    if (tid < 8) {
        int off = 0, pob = 0;
        #pragma unroll
        for (int t2 = 0; t2 < 8; t2++) {
            if (t2 == tid) pob = off;
            off += ((tots[t2] + 127) >> 7) << 7;
        }
        base[tid] = pob + pre;
        fill[tid] = 0;
        if (blk == 0) {
            po_out[tid] = pob;
            if (tid == 0) po_out[8] = off;
        }
    }
    __syncthreads();
    const int t = types[i];
    const int r = atomicAdd(&fill[t], 1);  // LDS atomic: intra-block rank
    const int p = base[t] + r;
    perm[p] = i;
    invperm[i] = p;
}

// ---------- fp8 GEMM (R11 = exact R9 restore; best passing config, 217.9 us) ---
// R10 lesson: fp8-quantizing the RESIDUAL stream (Xres) fails verification
// (absmax 0.028 > 0.012) -- fp8 is only legal for the two inner MLP matmuls.
// R8 lesson (HW): combined VGPR+AGPR floor ~170 -> launch_bounds(256,3) ONLY;
// (256,4)/(512,4) split the 128-reg budget 64V+64A and spill (WRITE +26MB).
// MX inner (m145/m148): one mfma_scale_f32_16x16x128_f8f6f4 with unit scales
// (E8M0 127 = 2^0) per fragment pair per K-tile; per-element K-order matches
// the original fp8 kernel -> bit-identical absmax 0.005859375.
// MODE 0 (GEMM1): 1D 2048-block XCD-band grid; A=Xb8 token-order;
//                 C = fp8(relu*0.125) scattered via invperm, k-rotated by p.
// MODE 1 (GEMM2): 1D 1056-block XCD-band grid; A=Xff8 bucket-order; B per
//                 bucket via po[]; epilogue: Xb[tok] += relu(acc)/512 (bf16).
template <int MODE>
__global__ __launch_bounds__(256, 3)
void gemm_fp8_kernel(const unsigned char* __restrict__ A,
                     const unsigned char* __restrict__ B,
                     void* __restrict__ Cout,
                     const unsigned short* __restrict__ xres,
                     const int* __restrict__ pmap,   // MODE0: invperm, MODE1: perm
                     const int* __restrict__ po,     // MODE1 only: padded offsets[9]
                     int K, int ldA) {
    __shared__ unsigned char As[128 * 128];
    __shared__ unsigned char Bs[128 * 128];
    __shared__ int ptile[128];

    const int tid  = threadIdx.x;
    const int wave = tid >> 6;
    const int lane = tid & 63;
    const int quad = lane >> 4;
    const int tl   = lane & 15;
    int m0, n0;
    if constexpr (MODE == 1) {
        // 1056 blocks; XCD-band swizzle (1056 % 8 == 0, bijective)
        const int sid = (blockIdx.x & 7) * 132 + (blockIdx.x >> 3);
        m0 = (sid >> 2) * 128;
        n0 = (sid & 3) * 128;
    } else {
        // 2048 blocks; XCD-band swizzle: XCD k owns 32 m-tiles x all 8 n-tiles
        const int sid = (blockIdx.x & 7) * 256 + (blockIdx.x >> 3);
        m0 = (sid >> 3) * 128;
        n0 = (sid & 7) * 128;
    }
    const int wm = (wave & 1) * 64;
    const int wn = (wave >> 1) * 64;

    const unsigned char* Bp = B;
    if constexpr (MODE == 1) {
        if (m0 >= po[8]) return;                  // fully-padded tail block
        int bsel = 0;
        #pragma unroll
        for (int i = 1; i < 8; i++) bsel += (m0 >= po[i]) ? 1 : 0;
        Bp = B + (size_t)bsel * (DIN * DFF);
    }
    if (tid < 128) ptile[tid] = pmap[m0 + tid];

    f32x4 acc[4][4];
    #pragma unroll
    for (int i = 0; i < 4; i++)
        #pragma unroll
        for (int j = 0; j < 4; j++)
            acc[i][j] = (f32x4){0.f, 0.f, 0.f, 0.f};

    for (int k0 = 0; k0 < K; k0 += 128) {
        __syncthreads();
        // A tile [128][128]: 1024 x 16B chunks, 4/thread, LINEAR copy
        #pragma unroll
        for (int i = 0; i < 4; i++) {
            const int c   = (i * 4 + wave) * 64 + lane;
            const int row = c >> 3;
            const int j   = c & 7;
            async16(A + (size_t)(m0 + row) * ldA + k0 + j * 16, (char*)As + (size_t)c * 16);
        }
        // B tile [128][128], linear
        #pragma unroll
        for (int i = 0; i < 4; i++) {
            const int c   = (i * 4 + wave) * 64 + lane;
            const int row = c >> 3;
            const int j   = c & 7;
            async16(Bp + (size_t)(n0 + row) * K + k0 + j * 16, (char*)Bs + (size_t)c * 16);
        }
        __syncthreads();

        // MX inner: lane covers k in [quad*32, quad*32+32) of this K-tile,
        // read as 4x8B rotated pieces (rotation multiple of 8 -> never wraps).
        frag8 bfr[4];
        #pragma unroll
        for (int nt = 0; nt < 4; nt++) {
            const unsigned char* bp = Bs + (wn + nt * 16 + tl) * 128;
            #pragma unroll
            for (int j = 0; j < 4; j++)
                bfr[nt].l[j] = *(const long*)(bp + ((quad * 32 + j * 8 + tl * 8) & 127));
        }
        #pragma unroll
        for (int mt = 0; mt < 4; mt++) {
            frag8 af;
            const unsigned char* ap = As + (wm + mt * 16 + tl) * 128;
            #pragma unroll
            for (int j = 0; j < 4; j++)
                af.l[j] = *(const long*)(ap + ((quad * 32 + j * 8 + tl * 8) & 127));
            #pragma unroll
            for (int nt = 0; nt < 4; nt++)
                acc[mt][nt] = __builtin_amdgcn_mfma_scale_f32_16x16x128_f8f6f4(
                    bfr[nt].v, af.v, acc[mt][nt],
                    0, 0,          // cbsz=fp8(e4m3), blgp=fp8(e4m3)
                    0, 127,        // scale_a: byte0 = 127 (2^0)
                    0, 127);       // scale_b: byte0 = 127 (2^0)  swapped: D[n][tok]
        }
    }

    // epilogue: lane holds 4 consecutive n (regs) for token tl
    if constexpr (MODE == 0) {
        unsigned char* C8 = (unsigned char*)Cout;
        #pragma unroll
        for (int mt = 0; mt < 4; mt++) {
            const int p = ptile[wm + mt * 16 + tl];            // bucket position
            const size_t rowbase = (size_t)p * DFF;
            const int prot = (p & 15) << 3;
            #pragma unroll
            for (int nt = 0; nt < 4; nt++) {
                const int off = wn + nt * 16 + quad * 4;       // in-window offset
                unsigned int pk = pk4_fp8(fmaxf(acc[mt][nt][0], 0.f) * 0.125f,
                                          fmaxf(acc[mt][nt][1], 0.f) * 0.125f,
                                          fmaxf(acc[mt][nt][2], 0.f) * 0.125f,
                                          fmaxf(acc[mt][nt][3], 0.f) * 0.125f);
                const int phys = (off & ~127) + (((off & 127) + prot) & 127);
                *(unsigned int*)(C8 + rowbase + n0 + phys) = pk;
            }
        }
    } else {
        unsigned short* Cb = (unsigned short*)Cout;
        int toks[4];
        #pragma unroll
        for (int mt = 0; mt < 4; mt++) toks[mt] = ptile[wm + mt * 16 + tl];
        // batch ALL residual loads first (breaks serial dependent chains)
        ushort4 rv[4][4];
        #pragma unroll
        for (int mt = 0; mt < 4; mt++) {
            if (toks[mt] < 0) continue;
            const size_t rowbase = (size_t)toks[mt] * DIN;
            #pragma unroll
            for (int nt = 0; nt < 4; nt++)
                rv[mt][nt] = *(const ushort4*)(xres + rowbase + n0 + wn + nt * 16 + quad * 4);
        }
        #pragma unroll
        for (int mt = 0; mt < 4; mt++) {
            if (toks[mt] < 0) continue;
            const size_t rowbase = (size_t)toks[mt] * DIN;
            #pragma unroll
            for (int nt = 0; nt < 4; nt++) {
                const int ncol = n0 + wn + nt * 16 + quad * 4;
                ushort4 o;
                o.x = f2bf(bf2f(rv[mt][nt].x) + fmaxf(acc[mt][nt][0], 0.f) * 0.001953125f);
                o.y = f2bf(bf2f(rv[mt][nt].y) + fmaxf(acc[mt][nt][1], 0.f) * 0.001953125f);
                o.z = f2bf(bf2f(rv[mt][nt].z) + fmaxf(acc[mt][nt][2], 0.f) * 0.001953125f);
                o.w = f2bf(bf2f(rv[mt][nt].w) + fmaxf(acc[mt][nt][3], 0.f) * 0.001953125f);
                *(ushort4*)(Cb + rowbase + ncol) = o;
            }
        }
    }
}

// ------- bf16 GEMM3 + head (kept full precision): 128x256 tile, 512 thr --------
// out[tok] += relu(Xb @ W_c1) . w2   (atomicAdd partials per n-block)
// 1D grid + XCD-band swizzle (512 % 8 == 0).
// R10 lesson: this stage must stay bf16 (fp8 residual fails verification).
__global__ __launch_bounds__(512, 4)
void gemm3_kernel(const unsigned short* __restrict__ A,
                  const unsigned short* __restrict__ B,
                  const float* __restrict__ w2,
                  float* __restrict__ outp,
                  int K, int ldA) {
    __shared__ unsigned short As[128 * 64];
    __shared__ unsigned short Bs[256 * 64];

    const int tid  = threadIdx.x;
    const int wave = tid >> 6;
    const int lane = tid & 63;
    const int quad = lane >> 4;
    const int tl   = lane & 15;
    const int sid = (blockIdx.x & 7) * 64 + (blockIdx.x >> 3);
    const int m0 = (sid >> 1) * 128;
    const int n0 = (sid & 1) * 256;
    const int wm = (wave & 1) * 64;
    const int wn = (wave >> 1) * 64;

    f32x4 acc[4][4];
    #pragma unroll
    for (int i = 0; i < 4; i++)
        #pragma unroll
        for (int j = 0; j < 4; j++)
            acc[i][j] = (f32x4){0.f, 0.f, 0.f, 0.f};

    for (int k0 = 0; k0 < K; k0 += 64) {
        __syncthreads();
        #pragma unroll
        for (int i = 0; i < 2; i++) {
            const int c   = (i * 8 + wave) * 64 + lane;
            const int row = c >> 3;
            const int gj  = (c & 7) ^ (row & 7);
            async16(A + (size_t)(m0 + row) * ldA + k0 + gj * 8, (char*)As + (size_t)c * 16);
        }
        #pragma unroll
        for (int i = 0; i < 4; i++) {
            const int c   = (i * 8 + wave) * 64 + lane;
            const int row = c >> 3;
            const int gj  = (c & 7) ^ (row & 7);
            async16(B + (size_t)(n0 + row) * K + k0 + gj * 8, (char*)Bs + (size_t)c * 16);
        }
        __syncthreads();

        #pragma unroll
        for (int ks = 0; ks < 2; ks++) {
            bf16x8 af[4], bfr[4];
            const int jc = ks * 4 + quad;
            #pragma unroll
            for (int t = 0; t < 4; t++) {
                const int r = wm + t * 16 + tl;
                af[t] = *(const bf16x8*)(As + (r * 8 + (jc ^ (r & 7))) * 8);
            }
            #pragma unroll
            for (int t = 0; t < 4; t++) {
                const int r = wn + t * 16 + tl;
                bfr[t] = *(const bf16x8*)(Bs + (r * 8 + (jc ^ (r & 7))) * 8);
            }
            #pragma unroll
            for (int mt = 0; mt < 4; mt++)
                #pragma unroll
                for (int nt = 0; nt < 4; nt++)
                    acc[mt][nt] = __builtin_amdgcn_mfma_f32_16x16x32_bf16(
                        bfr[nt], af[mt], acc[mt][nt], 0, 0, 0);
        }
    }

    float4 w2v[4];
    #pragma unroll
    for (int nt = 0; nt < 4; nt++)
        w2v[nt] = *(const float4*)(w2 + n0 + wn + nt * 16 + quad * 4);
    #pragma unroll
    for (int mt = 0; mt < 4; mt++) {
        float s = 0.f;
        #pragma unroll
        for (int nt = 0; nt < 4; nt++) {
            s += fmaxf(acc[mt][nt][0], 0.f) * w2v[nt].x;
            s += fmaxf(acc[mt][nt][1], 0.f) * w2v[nt].y;
            s += fmaxf(acc[mt][nt][2], 0.f) * w2v[nt].z;
            s += fmaxf(acc[mt][nt][3], 0.f) * w2v[nt].w;
        }
        s += __shfl_down(s, 32);
        s += __shfl_down(s, 16);
        if (lane < 16) atomicAdd(&outp[m0 + wm + mt * 16 + lane], s);
    }
}

extern "C" void kernel_launch(void* const* d_in, const int* in_sizes, int n_in,
                              void* d_out, int out_size, void* d_ws, size_t ws_size,
                              hipStream_t stream) {
    const float* x      = (const float*)d_in[0];
    const int*   types  = (const int*)d_in[1];
    const float* W_pre  = (const float*)d_in[2];
    const float* W_types= (const float*)d_in[3];
    const float* W_c1   = (const float*)d_in[4];
    const float* W_c2   = (const float*)d_in[5];
    float* out = (float*)d_out;

    // workspace layout (~91 MB):
    char* ws = (char*)d_ws;
    unsigned short* Xb  = (unsigned short*)(ws);                    // bf16 [32768][512], becomes X_res
    unsigned char*  Xff8= (unsigned char*)(ws + 33554432ull);       // fp8 [MPAD][1024] = 8*x_, bucket order, k-rotated
    unsigned char*  Xb8 = (unsigned char*)(ws + 68157440ull);       // fp8 [32768][512] = x, k-rotated
    unsigned char*  Wp8 = (unsigned char*)(ws + 84934656ull);       // fp8 [1024][512] (x64, rotated)
    unsigned char*  Wt8 = (unsigned char*)(ws + 85458944ull);       // fp8 [8][512][1024] (x64, rotated)
    unsigned short* WcT = (unsigned short*)(ws + 89653248ull);      // bf16 [512][512]
    int* perm           = (int*)(ws + 90177536ull);                  // MPAD ints
    int* invperm        = (int*)(ws + 90312704ull);                  // N_TOK ints
    int* po             = (int*)(ws + 90443776ull);                  // 9 ints (padded offsets)
    int* blockhist      = po + 16;                                   // 64*8 ints

    // 1) merged prep: tokens [0,16384), weights [16384,26624), perm-pad [26624,26756)
    prep_kernel<<<26756, 256, 0, stream>>>(x, Xb, Xb8, types, blockhist,
                                           W_pre, W_types, W_c1, Wp8, Wt8, WcT, perm);
    // 2) deterministic scatter + po publish + out zero
    scatter_kernel<<<64, 512, 0, stream>>>(types, blockhist, perm, invperm, out, po);
    // 3) GEMM1 (fp8 MX, R6 body, XCD-banded grid): Xff8[invperm[tok]] = fp8(8 * relu(x @ W_pre))
    gemm_fp8_kernel<0><<<2048, 256, 0, stream>>>(
        Xb8, Wp8, Xff8, nullptr, invperm, nullptr, 512, 512);
    // 4) GEMM2 (fp8 MX, routed, exact R6): Xb = bf16(Xb + relu(Xff8 @ Wt8[b]) / 512)
    gemm_fp8_kernel<1><<<1056, 256, 0, stream>>>(
        Xff8, Wt8, Xb, Xb, perm, po, 1024, 1024);
    // 5) GEMM3 + head (bf16, XCD-banded 1D grid): out = relu(Xb @ W_c1) @ W_c2
    gemm3_kernel<<<512, 512, 0, stream>>>(
        Xb, WcT, W_c2, out, 512, 512);
}